// Round 17
// baseline (628.382 us; speedup 1.0000x reference)
//
#include <hip/hip_runtime.h>
#include <math.h>

#define N 8192
#define C 128
#define NC 256
#define KNN 5

#define TP 128                        // tile size
#define NTILE (N / TP)                // 64
#define NPAIR (NTILE * (NTILE + 1) / 2)   // 2080
#define CH 16                         // channels per staging chunk
#define PA 130                        // A LDS pitch (doubles)
#define PB 66                         // B LDS pitch (doubles)
#define SQRT_C 11.313708498984761     // sqrt(128)

typedef double d4 __attribute__((ext_vector_type(4)));

static __device__ __forceinline__ unsigned rotl32(unsigned x, unsigned r) {
    return (x << r) | (x >> (32u - r));
}

// order-preserving double -> uint64 map (ascending)
static __device__ __forceinline__ unsigned long long dmap(double x) {
    long long b = __double_as_longlong(x);
    unsigned long long u = (unsigned long long)b;
    return (b >= 0) ? (u | 0x8000000000000000ull) : ~u;
}
static __device__ __forceinline__ double dunmap(unsigned long long u) {
    if (u & 0x8000000000000000ull) return __longlong_as_double((long long)(u ^ 0x8000000000000000ull));
    return __longlong_as_double((long long)(~u));
}

// ---------------------------------------------------------------------------
// Branchless sorted top-5 (ascending).  (proven R13)
static __device__ __forceinline__ void ins5s(double (&m)[KNN], double v) {
    m[4] = fmin(m[4], fmax(m[3], v));
    m[3] = fmin(m[3], fmax(m[2], v));
    m[2] = fmin(m[2], fmax(m[1], v));
    m[1] = fmin(m[1], fmax(m[0], v));
    m[0] = fmin(m[0], v);
}
static __device__ __forceinline__ void sort5(double (&m)[KNN]) {
    double lo, hi;
#define CE(i, j) lo = fmin(m[i], m[j]); hi = fmax(m[i], m[j]); m[i] = lo; m[j] = hi;
    CE(0,1) CE(3,4) CE(2,4) CE(2,3) CE(0,3) CE(0,2) CE(1,4) CE(1,3) CE(1,2)
#undef CE
}
// bitonic top-5 butterfly merge (snapshot-before-mutate)  (proven R13)
static __device__ __forceinline__ void bfly5s(double (&m)[KNN], int mask) {
    double pv[KNN];
    #pragma unroll
    for (int k = 0; k < KNN; k++) pv[k] = __shfl_xor(m[4 - k], mask, 64);
    #pragma unroll
    for (int k = 0; k < KNN; k++) m[k] = fmin(m[k], pv[k]);
    sort5(m);
}
static __device__ __forceinline__ void merge5s(double (&m)[KNN], const double* l) {
    #pragma unroll
    for (int k = 0; k < KNN; k++) m[k] = fmin(m[k], l[4 - k]);
    sort5(m);
}

// ---------------------------------------------------------------------------
// f64 MFMA D-layout probe (proven R15): A[m][k]=m, B[k][n]=[n==0] -> D[i][0]=4i.
static __device__ __forceinline__ void probe_rows(int t, int r, int (&irow)[4]) {
    d4 pd = (d4){0.0, 0.0, 0.0, 0.0};
    pd = __builtin_amdgcn_mfma_f64_16x16x4f64((double)r, (r == 0) ? 1.0 : 0.0,
                                              pd, 0, 0, 0);
    #pragma unroll
    for (int j = 0; j < 4; j++) {
        double rv = __shfl(pd[j], t & 48, 64);   // group root lane 16*g
        irow[j] = (int)(rv * 0.25);
    }
}

// ---------------------------------------------------------------------------
__global__ void init_kernel(unsigned long long* d2max, unsigned long long* gmin) {
    int i = blockIdx.x * blockDim.x + threadIdx.x;
    if (i < N) gmin[i] = 0xFFFFFFFFFFFFFFFFull;
    if (i == 0) *d2max = 0ull;
}

// ---------------------------------------------------------------------------
__global__ void sq_kernel(const float* __restrict__ X, double* __restrict__ sq) {
    int wave = (blockIdx.x * blockDim.x + threadIdx.x) >> 6;
    int lane = threadIdx.x & 63;
    if (wave >= N) return;
    double v0 = (double)X[wave * C + lane];
    double v1 = (double)X[wave * C + 64 + lane];
    double s = v0 * v0 + v1 * v1;
    #pragma unroll
    for (int off = 32; off > 0; off >>= 1) s += __shfl_down(s, off, 64);
    if (lane == 0) sq[wave] = s;
}

// ---------------------------------------------------------------------------
// JAX threefry2x32: uniform(key(1), (1,8192))
// ---------------------------------------------------------------------------
__global__ void noise_kernel(float* __restrict__ noise) {
    int j = blockIdx.x * blockDim.x + threadIdx.x;
    if (j >= N / 2) return;
    const unsigned ks0 = 0u, ks1 = 1u;
    const unsigned ks2 = 0x1BD11BDAu ^ ks0 ^ ks1;
    unsigned x0 = (unsigned)j + ks0;
    unsigned x1 = (unsigned)(j + N / 2) + ks1;
    const unsigned rotA[4] = {13u, 15u, 26u, 6u};
    const unsigned rotB[4] = {17u, 29u, 16u, 24u};
    #pragma unroll
    for (int r = 0; r < 4; r++) { x0 += x1; x1 = rotl32(x1, rotA[r]); x1 ^= x0; }
    x0 += ks1; x1 += ks2 + 1u;
    #pragma unroll
    for (int r = 0; r < 4; r++) { x0 += x1; x1 = rotl32(x1, rotB[r]); x1 ^= x0; }
    x0 += ks2; x1 += ks0 + 2u;
    #pragma unroll
    for (int r = 0; r < 4; r++) { x0 += x1; x1 = rotl32(x1, rotA[r]); x1 ^= x0; }
    x0 += ks0; x1 += ks1 + 3u;
    #pragma unroll
    for (int r = 0; r < 4; r++) { x0 += x1; x1 = rotl32(x1, rotB[r]); x1 ^= x0; }
    x0 += ks1; x1 += ks2 + 4u;
    #pragma unroll
    for (int r = 0; r < 4; r++) { x0 += x1; x1 = rotl32(x1, rotA[r]); x1 ^= x0; }
    x0 += ks2; x1 += ks0 + 5u;
    unsigned b0 = (x0 >> 9) | 0x3f800000u;
    unsigned b1 = (x1 >> 9) | 0x3f800000u;
    noise[j]         = __uint_as_float(b0) - 1.0f;
    noise[j + N / 2] = __uint_as_float(b1) - 1.0f;
}

// p = bj*(bj+1)/2 + bi, bi <= bj
static __device__ __forceinline__ void pair_decode(int p, int& bi, int& bj) {
    int b = (int)((sqrt(8.0 * (double)p + 1.0) - 1.0) * 0.5);
    while ((b + 1) * (b + 2) / 2 <= p) b++;
    while (b * (b + 1) / 2 > p) b--;
    bj = b;
    bi = p - b * (b + 1) / 2;
}

// ---------------------------------------------------------------------------
// Half-pass MFMA f64 GEMM: full 128-row A tile x 64-col B half-tile.
// acc[2][4] d4 (64 AGPR).  8 chunks of 16 channels, register prefetch.
// A: m=l&15, k=l>>4 ; B: k=l>>4, n=l&15 ; D: col=l&15, row via probe_rows.
// ---------------------------------------------------------------------------
#define MFMA_GEMM_HALF(acc, As, Bs, X4, i0, jh0, t, r, g, w32)                 \
    {                                                                          \
        float4 pa[2], pb;                                                      \
        _Pragma("unroll")                                                      \
        for (int q = 0; q < 2; q++) {                                          \
            int flat = t + 256 * q;                                            \
            int row = flat >> 2, c4 = flat & 3;                                \
            pa[q] = X4[(size_t)(i0 + row) * 32 + c4];                          \
        }                                                                      \
        {                                                                      \
            int brow = t >> 2, c4 = t & 3;                                     \
            pb = X4[(size_t)(jh0 + brow) * 32 + c4];                           \
        }                                                                      \
        for (int ck = 0; ck < 8; ck++) {                                       \
            _Pragma("unroll")                                                  \
            for (int q = 0; q < 2; q++) {                                      \
                int flat = t + 256 * q;                                        \
                int row = flat >> 2, c4 = flat & 3;                            \
                As[(4 * c4 + 0) * PA + row] = (double)pa[q].x;                 \
                As[(4 * c4 + 1) * PA + row] = (double)pa[q].y;                 \
                As[(4 * c4 + 2) * PA + row] = (double)pa[q].z;                 \
                As[(4 * c4 + 3) * PA + row] = (double)pa[q].w;                 \
            }                                                                  \
            {                                                                  \
                int brow = t >> 2, c4 = t & 3;                                 \
                Bs[(4 * c4 + 0) * PB + brow] = (double)pb.x;                   \
                Bs[(4 * c4 + 1) * PB + brow] = (double)pb.y;                   \
                Bs[(4 * c4 + 2) * PB + brow] = (double)pb.z;                   \
                Bs[(4 * c4 + 3) * PB + brow] = (double)pb.w;                   \
            }                                                                  \
            __syncthreads();                                                   \
            if (ck < 7) {                                                      \
                _Pragma("unroll")                                              \
                for (int q = 0; q < 2; q++) {                                  \
                    int flat = t + 256 * q;                                    \
                    int row = flat >> 2, c4 = flat & 3;                        \
                    pa[q] = X4[(size_t)(i0 + row) * 32 + (ck + 1) * 4 + c4];   \
                }                                                              \
                int brow = t >> 2, c4 = t & 3;                                 \
                pb = X4[(size_t)(jh0 + brow) * 32 + (ck + 1) * 4 + c4];        \
            }                                                                  \
            _Pragma("unroll")                                                  \
            for (int ks = 0; ks < 4; ks++) {                                   \
                int cc = 4 * ks + g;                                           \
                double a0 = As[cc * PA + w32 + r];                             \
                double a1 = As[cc * PA + w32 + 16 + r];                        \
                double bv[4];                                                  \
                _Pragma("unroll")                                              \
                for (int nt = 0; nt < 4; nt++)                                 \
                    bv[nt] = Bs[cc * PB + nt * 16 + r];                        \
                _Pragma("unroll")                                              \
                for (int nt = 0; nt < 4; nt++)                                 \
                    acc[0][nt] = __builtin_amdgcn_mfma_f64_16x16x4f64(a0, bv[nt], acc[0][nt], 0, 0, 0); \
                _Pragma("unroll")                                              \
                for (int nt = 0; nt < 4; nt++)                                 \
                    acc[1][nt] = __builtin_amdgcn_mfma_f64_16x16x4f64(a1, bv[nt], acc[1][nt], 0, 0, 0); \
            }                                                                  \
            __syncthreads();                                                   \
        }                                                                      \
    }

// lane-owned outputs: rows w32 + mt*16 + irow[j], cols (half h): h*64 + nt*16 + r

// ---------------------------------------------------------------------------
// symA: two half-passes; rows -> rec_dir[(2p+h)][row], cols -> rec_tr[p][col].
// ---------------------------------------------------------------------------
__launch_bounds__(256, 3)
__global__ void symA_kernel(const float* __restrict__ X,
                            const double* __restrict__ sq,
                            double* __restrict__ rec_dir,
                            double* __restrict__ rec_tr,
                            unsigned long long* __restrict__ d2max_p)
{
    __shared__ __align__(16) double S[CH * PA + CH * PB];   // 25,088 B; M reuse
    double* As = S;
    double* Bs = S + CH * PA;
    const int t = threadIdx.x;
    const int r = t & 15;
    const int g = (t >> 4) & 3;
    const int w = t >> 6;
    const int w32 = w * 32;
    int bi, bj;
    pair_decode(blockIdx.x, bi, bj);
    const int i0 = bi * TP, j0 = bj * TP;
    const float4* X4 = (const float4*)X;

    int irow[4];
    probe_rows(t, r, irow);

    double sqa[2][4];
    #pragma unroll
    for (int mt = 0; mt < 2; mt++)
        #pragma unroll
        for (int j = 0; j < 4; j++) sqa[mt][j] = sq[i0 + w32 + mt * 16 + irow[j]];

    double rmax = 0.0;

    #pragma unroll 1
    for (int h = 0; h < 2; h++) {
        const int jh0 = j0 + h * 64;
        d4 acc[2][4];
        #pragma unroll
        for (int mt = 0; mt < 2; mt++)
            #pragma unroll
            for (int nt = 0; nt < 4; nt++) acc[mt][nt] = (d4){0.0, 0.0, 0.0, 0.0};

        MFMA_GEMM_HALF(acc, As, Bs, X4, i0, jh0, t, r, g, w32)

        double sqj[4];
        #pragma unroll
        for (int nt = 0; nt < 4; nt++) sqj[nt] = sq[jh0 + nt * 16 + r];
        #pragma unroll
        for (int mt = 0; mt < 2; mt++)
            #pragma unroll
            for (int nt = 0; nt < 4; nt++)
                #pragma unroll
                for (int j = 0; j < 4; j++) {
                    double v = sqa[mt][j] + sqj[nt] - 2.0 * acc[mt][nt][j];
                    acc[mt][nt][j] = v;
                    rmax = fmax(rmax, v);
                }

        // rows: scan 4 nt; bfly over r lanes; r==0 writes half-record
        #pragma unroll
        for (int mt = 0; mt < 2; mt++)
            #pragma unroll
            for (int j = 0; j < 4; j++) {
                double m5[KNN];
                #pragma unroll
                for (int k = 0; k < KNN; k++) m5[k] = 1e300;
                #pragma unroll
                for (int nt = 0; nt < 4; nt++) ins5s(m5, acc[mt][nt][j]);
                bfly5s(m5, 1); bfly5s(m5, 2); bfly5s(m5, 4); bfly5s(m5, 8);
                if (r == 0) {
                    int row = w32 + mt * 16 + irow[j];
                    double* outp = &rec_dir[((size_t)2 * blockIdx.x + h) * (TP * KNN) + row * KNN];
                    #pragma unroll
                    for (int k = 0; k < KNN; k++) outp[k] = m5[k];
                }
            }

        // cols (off-diagonal): scan 8 (mt,j); bfly over g; LDS merge of 4 waves
        if (bi != bj) {
            double* M = S;   // [col64][21] = 1344 dbl, fits in S
            #pragma unroll
            for (int nt = 0; nt < 4; nt++) {
                double m5[KNN];
                #pragma unroll
                for (int k = 0; k < KNN; k++) m5[k] = 1e300;
                #pragma unroll
                for (int mt = 0; mt < 2; mt++)
                    #pragma unroll
                    for (int j = 0; j < 4; j++) ins5s(m5, acc[mt][nt][j]);
                bfly5s(m5, 16); bfly5s(m5, 32);
                if (g == 0) {
                    int col = nt * 16 + r;   // 0..63 within half
                    #pragma unroll
                    for (int k = 0; k < KNN; k++) M[col * 21 + w * 5 + k] = m5[k];
                }
            }
            __syncthreads();
            if (t < 64) {
                double m5[KNN];
                #pragma unroll
                for (int k = 0; k < KNN; k++) m5[k] = M[t * 21 + k];
                merge5s(m5, &M[t * 21 + 5]);
                merge5s(m5, &M[t * 21 + 10]);
                merge5s(m5, &M[t * 21 + 15]);
                double* outp = &rec_tr[(size_t)blockIdx.x * (TP * KNN) + (h * 64 + t) * KNN];
                #pragma unroll
                for (int k = 0; k < KNN; k++) outp[k] = m5[k];
            }
            __syncthreads();   // M readers done before next half restages S
        }
    }

    #pragma unroll
    for (int off = 32; off > 0; off >>= 1) rmax = fmax(rmax, __shfl_down(rmax, off, 64));
    if ((t & 63) == 0)
        atomicMax(d2max_p, (unsigned long long)__double_as_longlong(fmax(rmax, 0.0)));
}

// ---------------------------------------------------------------------------
// Merge symA records -> density.  One WAVE per row.  Lane l:
//   l < 64-T : dir pair bj=T+l -> merge its two half-records
//   else     : tr record b2 = l-(64-T)
// then 6 butterfly stages; lane 0 computes density.
// ---------------------------------------------------------------------------
__global__ void density_merge_sym_kernel(const double* __restrict__ rec_dir,
                                         const double* __restrict__ rec_tr,
                                         const float* __restrict__ noise,
                                         double* __restrict__ density)
{
    int i = (blockIdx.x * blockDim.x + threadIdx.x) >> 6;
    int l = threadIdx.x & 63;
    if (i >= N) return;
    int T = i >> 7, rr = i & 127;
    int ndir = NTILE - T;
    double m5[KNN];
    if (l < ndir) {
        int bj = T + l;
        size_t p = (size_t)bj * (bj + 1) / 2 + T;
        const double* rp = &rec_dir[(2 * p) * (TP * KNN) + rr * KNN];
        #pragma unroll
        for (int k = 0; k < KNN; k++) m5[k] = rp[k];
        merge5s(m5, &rec_dir[(2 * p + 1) * (TP * KNN) + rr * KNN]);
    } else {
        int b2 = l - ndir;   // < T
        size_t cumT = (size_t)T * (T + 1) / 2;
        const double* rp = &rec_tr[(cumT + b2) * (TP * KNN) + rr * KNN];
        #pragma unroll
        for (int k = 0; k < KNN; k++) m5[k] = rp[k];
    }
    bfly5s(m5, 1); bfly5s(m5, 2); bfly5s(m5, 4);
    bfly5s(m5, 8); bfly5s(m5, 16); bfly5s(m5, 32);
    if (l == 0) {
        double s2 = 0.0;
        #pragma unroll
        for (int k = 0; k < KNN; k++) {
            double z = m5[k] > 0.0 ? m5[k] : 0.0;
            double d = sqrt(z) / SQRT_C;
            s2 += d * d;
        }
        density[i] = exp(-s2 / 5.0) + (double)(noise[i] * 1e-6f);
    }
}

// ---------------------------------------------------------------------------
// symB: two half-passes; masked row/col mins, shuffle-reduced, atomicMin.
// density read from global (L2-hot).
// ---------------------------------------------------------------------------
__launch_bounds__(256, 3)
__global__ void symB_kernel(const float* __restrict__ X,
                            const double* __restrict__ sq,
                            const double* __restrict__ density,
                            unsigned long long* __restrict__ gmin)
{
    __shared__ __align__(16) double S[CH * PA + CH * PB];
    double* As = S;
    double* Bs = S + CH * PA;
    const int t = threadIdx.x;
    const int r = t & 15;
    const int g = (t >> 4) & 3;
    const int w = t >> 6;
    const int w32 = w * 32;
    int bi, bj;
    pair_decode(blockIdx.x, bi, bj);
    const int i0 = bi * TP, j0 = bj * TP;
    const float4* X4 = (const float4*)X;

    int irow[4];
    probe_rows(t, r, irow);

    double sqa[2][4], di[2][4], dmr[2][4];
    #pragma unroll
    for (int mt = 0; mt < 2; mt++)
        #pragma unroll
        for (int j = 0; j < 4; j++) {
            int row = w32 + mt * 16 + irow[j];
            sqa[mt][j] = sq[i0 + row];
            di[mt][j] = density[i0 + row];
            dmr[mt][j] = 1e300;
        }

    #pragma unroll 1
    for (int h = 0; h < 2; h++) {
        const int jh0 = j0 + h * 64;
        d4 acc[2][4];
        #pragma unroll
        for (int mt = 0; mt < 2; mt++)
            #pragma unroll
            for (int nt = 0; nt < 4; nt++) acc[mt][nt] = (d4){0.0, 0.0, 0.0, 0.0};

        MFMA_GEMM_HALF(acc, As, Bs, X4, i0, jh0, t, r, g, w32)

        double sqj[4], dj[4], dmc[4];
        #pragma unroll
        for (int nt = 0; nt < 4; nt++) {
            int col = nt * 16 + r;
            sqj[nt] = sq[jh0 + col];
            dj[nt] = density[jh0 + col];
            dmc[nt] = 1e300;
        }
        #pragma unroll
        for (int mt = 0; mt < 2; mt++)
            #pragma unroll
            for (int nt = 0; nt < 4; nt++)
                #pragma unroll
                for (int j = 0; j < 4; j++) {
                    double v = sqa[mt][j] + sqj[nt] - 2.0 * acc[mt][nt][j];
                    if (dj[nt] > di[mt][j]) dmr[mt][j] = fmin(dmr[mt][j], v);
                    if (di[mt][j] > dj[nt]) dmc[nt] = fmin(dmc[nt], v);
                }

        // cols: bfly over g; g==0 atomicMin (per half)
        if (bi != bj) {
            #pragma unroll
            for (int nt = 0; nt < 4; nt++) {
                #pragma unroll
                for (int m = 16; m <= 32; m <<= 1)
                    dmc[nt] = fmin(dmc[nt], __shfl_xor(dmc[nt], m, 64));
            }
            if (g == 0) {
                #pragma unroll
                for (int nt = 0; nt < 4; nt++)
                    if (dmc[nt] < 9.9e299)
                        atomicMin(&gmin[jh0 + nt * 16 + r], dmap(dmc[nt]));
            }
        }
    }

    // rows: bfly over r lanes; r==0 atomicMin
    #pragma unroll
    for (int mt = 0; mt < 2; mt++)
        #pragma unroll
        for (int j = 0; j < 4; j++) {
            #pragma unroll
            for (int m = 1; m <= 8; m <<= 1)
                dmr[mt][j] = fmin(dmr[mt][j], __shfl_xor(dmr[mt][j], m, 64));
        }
    if (r == 0) {
        #pragma unroll
        for (int mt = 0; mt < 2; mt++)
            #pragma unroll
            for (int j = 0; j < 4; j++)
                if (dmr[mt][j] < 9.9e299) {
                    int row = w32 + mt * 16 + irow[j];
                    atomicMin(&gmin[i0 + row], dmap(dmr[mt][j]));
                }
    }
}

// ---------------------------------------------------------------------------
__global__ void score_sym_kernel(const unsigned long long* __restrict__ gmin,
                                 const double* __restrict__ density,
                                 const unsigned long long* __restrict__ d2max_p,
                                 double* __restrict__ score)
{
    int i = blockIdx.x * blockDim.x + threadIdx.x;
    if (i >= N) return;
    unsigned long long u = gmin[i];
    double d2m = __longlong_as_double((long long)(*d2max_p));
    double distmax = sqrt(fmax(d2m, 0.0)) / SQRT_C;
    double dp;
    if (u == 0xFFFFFFFFFFFFFFFFull) {
        dp = distmax;
    } else {
        double dmin = dunmap(u);
        dp = sqrt(fmax(dmin, 0.0)) / SQRT_C;
    }
    score[i] = dp * density[i];
}

// ---------------------------------------------------------------------------
// Stable descending rank; 256 blocks, 8-way j-split per row, shuffle reduce.
// ---------------------------------------------------------------------------
__launch_bounds__(256)
__global__ void rank_kernel(const double* __restrict__ score, int* __restrict__ out)
{
    __shared__ double Ss[N];   // 64 KB
    for (int k = 0; k < N / 256; k++) {
        int idx = threadIdx.x + 256 * k;
        Ss[idx] = score[idx];
    }
    __syncthreads();
    int il = threadIdx.x >> 3;          // 0..31
    int ch = threadIdx.x & 7;           // 0..7
    int i = blockIdx.x * 32 + il;
    double si = Ss[i];
    int cnt = 0;
    for (int q = 0; q < N / 8; q++) {
        int j = ch + (q << 3);
        double sj = Ss[j];
        cnt += (sj > si) || (sj == si && j < i);
    }
    cnt += __shfl_down(cnt, 4, 8);
    cnt += __shfl_down(cnt, 2, 8);
    cnt += __shfl_down(cnt, 1, 8);
    if (ch == 0 && cnt < NC) out[cnt] = i;
}

// ---------------------------------------------------------------------------
extern "C" void kernel_launch(void* const* d_in, const int* in_sizes, int n_in,
                              void* d_out, int out_size, void* d_ws, size_t ws_size,
                              hipStream_t stream) {
    const float* X = (const float*)d_in[0];
    int* out = (int*)d_out;

    double* ws      = (double*)d_ws;
    double* sq      = ws;                      // 8192
    double* density = ws + 8192;               // 8192
    double* score   = ws + 16384;              // 8192
    unsigned long long* d2max = (unsigned long long*)(ws + 24576);
    unsigned long long* gmin  = (unsigned long long*)(ws + 24584);  // 8192
    float*  noise   = (float*)(ws + 32776);    // 8192 floats

    const size_t rec_dir_bytes = (size_t)2 * NPAIR * TP * KNN * sizeof(double);  // 21.3 MB
    const size_t base_need = 4ull * 1024 * 1024;
    double* rec_dir = (double*)((char*)d_ws + base_need);
    double* rec_tr  = (double*)((char*)d_ws + base_need + rec_dir_bytes);        // +10.65 MB

    init_kernel<<<N / 256, 256, 0, stream>>>(d2max, gmin);
    sq_kernel<<<N / 4, 256, 0, stream>>>(X, sq);
    noise_kernel<<<(N / 2) / 256, 256, 0, stream>>>(noise);

    symA_kernel<<<NPAIR, 256, 0, stream>>>(X, sq, rec_dir, rec_tr, d2max);
    density_merge_sym_kernel<<<N * 64 / 256, 256, 0, stream>>>(rec_dir, rec_tr, noise, density);
    symB_kernel<<<NPAIR, 256, 0, stream>>>(X, sq, density, gmin);
    score_sym_kernel<<<N / 256, 256, 0, stream>>>(gmin, density, d2max, score);
    rank_kernel<<<N / 32, 256, 0, stream>>>(score, out);
}

// Round 18
// 493.016 us; speedup vs baseline: 1.2746x; 1.2746x over previous
//
#include <hip/hip_runtime.h>
#include <math.h>

#define N 8192
#define C 128
#define NC 256
#define KNN 5

#define TP 128                        // tile size
#define NTILE (N / TP)                // 64
#define NPAIR (NTILE * (NTILE + 1) / 2)   // 2080
#define CH 16                         // channels per staging chunk
#define PJ 130                        // LDS pitch over row-dim (doubles)
#define SQRT_C 11.313708498984761     // sqrt(128)

typedef double d4 __attribute__((ext_vector_type(4)));

static __device__ __forceinline__ unsigned rotl32(unsigned x, unsigned r) {
    return (x << r) | (x >> (32u - r));
}

// order-preserving double -> uint64 map (ascending)
static __device__ __forceinline__ unsigned long long dmap(double x) {
    long long b = __double_as_longlong(x);
    unsigned long long u = (unsigned long long)b;
    return (b >= 0) ? (u | 0x8000000000000000ull) : ~u;
}
static __device__ __forceinline__ double dunmap(unsigned long long u) {
    if (u & 0x8000000000000000ull) return __longlong_as_double((long long)(u ^ 0x8000000000000000ull));
    return __longlong_as_double((long long)(~u));
}

// ---------------------------------------------------------------------------
// Branchless sorted top-5 (ascending).  (proven R13)
static __device__ __forceinline__ void ins5s(double (&m)[KNN], double v) {
    m[4] = fmin(m[4], fmax(m[3], v));
    m[3] = fmin(m[3], fmax(m[2], v));
    m[2] = fmin(m[2], fmax(m[1], v));
    m[1] = fmin(m[1], fmax(m[0], v));
    m[0] = fmin(m[0], v);
}
static __device__ __forceinline__ void sort5(double (&m)[KNN]) {
    double lo, hi;
#define CE(i, j) lo = fmin(m[i], m[j]); hi = fmax(m[i], m[j]); m[i] = lo; m[j] = hi;
    CE(0,1) CE(3,4) CE(2,4) CE(2,3) CE(0,3) CE(0,2) CE(1,4) CE(1,3) CE(1,2)
#undef CE
}
// bitonic top-5 butterfly merge (snapshot-before-mutate)  (proven R13)
static __device__ __forceinline__ void bfly5s(double (&m)[KNN], int mask) {
    double pv[KNN];
    #pragma unroll
    for (int k = 0; k < KNN; k++) pv[k] = __shfl_xor(m[4 - k], mask, 64);
    #pragma unroll
    for (int k = 0; k < KNN; k++) m[k] = fmin(m[k], pv[k]);
    sort5(m);
}
static __device__ __forceinline__ void merge5s(double (&m)[KNN], const double* l) {
    #pragma unroll
    for (int k = 0; k < KNN; k++) m[k] = fmin(m[k], l[4 - k]);
    sort5(m);
}

// ---------------------------------------------------------------------------
// f64 MFMA D-layout probe (proven R15): A[m][k]=m, B[k][n]=[n==0] -> D[i][0]=4i.
static __device__ __forceinline__ void probe_rows(int t, int r, int (&irow)[4]) {
    d4 pd = (d4){0.0, 0.0, 0.0, 0.0};
    pd = __builtin_amdgcn_mfma_f64_16x16x4f64((double)r, (r == 0) ? 1.0 : 0.0,
                                              pd, 0, 0, 0);
    #pragma unroll
    for (int j = 0; j < 4; j++) {
        double rv = __shfl(pd[j], t & 48, 64);   // group root lane 16*g
        irow[j] = (int)(rv * 0.25);
    }
}

// ---------------------------------------------------------------------------
__global__ void init_kernel(unsigned long long* d2max, unsigned long long* gmin) {
    int i = blockIdx.x * blockDim.x + threadIdx.x;
    if (i < N) gmin[i] = 0xFFFFFFFFFFFFFFFFull;
    if (i == 0) *d2max = 0ull;
}

// ---------------------------------------------------------------------------
__global__ void sq_kernel(const float* __restrict__ X, double* __restrict__ sq) {
    int wave = (blockIdx.x * blockDim.x + threadIdx.x) >> 6;
    int lane = threadIdx.x & 63;
    if (wave >= N) return;
    double v0 = (double)X[wave * C + lane];
    double v1 = (double)X[wave * C + 64 + lane];
    double s = v0 * v0 + v1 * v1;
    #pragma unroll
    for (int off = 32; off > 0; off >>= 1) s += __shfl_down(s, off, 64);
    if (lane == 0) sq[wave] = s;
}

// ---------------------------------------------------------------------------
// JAX threefry2x32: uniform(key(1), (1,8192))
// ---------------------------------------------------------------------------
__global__ void noise_kernel(float* __restrict__ noise) {
    int j = blockIdx.x * blockDim.x + threadIdx.x;
    if (j >= N / 2) return;
    const unsigned ks0 = 0u, ks1 = 1u;
    const unsigned ks2 = 0x1BD11BDAu ^ ks0 ^ ks1;
    unsigned x0 = (unsigned)j + ks0;
    unsigned x1 = (unsigned)(j + N / 2) + ks1;
    const unsigned rotA[4] = {13u, 15u, 26u, 6u};
    const unsigned rotB[4] = {17u, 29u, 16u, 24u};
    #pragma unroll
    for (int r = 0; r < 4; r++) { x0 += x1; x1 = rotl32(x1, rotA[r]); x1 ^= x0; }
    x0 += ks1; x1 += ks2 + 1u;
    #pragma unroll
    for (int r = 0; r < 4; r++) { x0 += x1; x1 = rotl32(x1, rotB[r]); x1 ^= x0; }
    x0 += ks2; x1 += ks0 + 2u;
    #pragma unroll
    for (int r = 0; r < 4; r++) { x0 += x1; x1 = rotl32(x1, rotA[r]); x1 ^= x0; }
    x0 += ks0; x1 += ks1 + 3u;
    #pragma unroll
    for (int r = 0; r < 4; r++) { x0 += x1; x1 = rotl32(x1, rotB[r]); x1 ^= x0; }
    x0 += ks1; x1 += ks2 + 4u;
    #pragma unroll
    for (int r = 0; r < 4; r++) { x0 += x1; x1 = rotl32(x1, rotA[r]); x1 ^= x0; }
    x0 += ks2; x1 += ks0 + 5u;
    unsigned b0 = (x0 >> 9) | 0x3f800000u;
    unsigned b1 = (x1 >> 9) | 0x3f800000u;
    noise[j]         = __uint_as_float(b0) - 1.0f;
    noise[j + N / 2] = __uint_as_float(b1) - 1.0f;
}

// p = bj*(bj+1)/2 + bi, bi <= bj
static __device__ __forceinline__ void pair_decode(int p, int& bi, int& bj) {
    int b = (int)((sqrt(8.0 * (double)p + 1.0) - 1.0) * 0.5);
    while ((b + 1) * (b + 2) / 2 <= p) b++;
    while (b * (b + 1) / 2 > p) b--;
    bj = b;
    bi = p - b * (b + 1) / 2;
}

// ---------------------------------------------------------------------------
// MFMA f64 GEMM body (R15, proven 49% MfmaUtil): 128x128 tile-pair.
// Wave w owns rows w*32..w*32+31 (2 row-tiles) x all 128 cols (8 col-tiles).
// acc[2][8] d4/lane.  f64 [c][row] staging (pitch PJ), 8 chunks of 16
// channels, register prefetch.  A: m=l&15,k=l>>4 ; B: k=l>>4,n=l&15 ;
// D: col=l&15, row via probe_rows.
// ---------------------------------------------------------------------------
#define MFMA_GEMM_BODY(acc, As, Bs, X4, i0, j0, t, r, g, w32)                  \
    {                                                                          \
        float4 pa[2], pb[2];                                                   \
        _Pragma("unroll")                                                      \
        for (int q = 0; q < 2; q++) {                                          \
            int flat = t + 256 * q;                                            \
            int row = flat >> 2, c4 = flat & 3;                                \
            pa[q] = X4[(size_t)(i0 + row) * 32 + c4];                          \
            pb[q] = X4[(size_t)(j0 + row) * 32 + c4];                          \
        }                                                                      \
        for (int ck = 0; ck < 8; ck++) {                                       \
            _Pragma("unroll")                                                  \
            for (int q = 0; q < 2; q++) {                                      \
                int flat = t + 256 * q;                                        \
                int row = flat >> 2, c4 = flat & 3;                            \
                As[(4 * c4 + 0) * PJ + row] = (double)pa[q].x;                 \
                As[(4 * c4 + 1) * PJ + row] = (double)pa[q].y;                 \
                As[(4 * c4 + 2) * PJ + row] = (double)pa[q].z;                 \
                As[(4 * c4 + 3) * PJ + row] = (double)pa[q].w;                 \
                Bs[(4 * c4 + 0) * PJ + row] = (double)pb[q].x;                 \
                Bs[(4 * c4 + 1) * PJ + row] = (double)pb[q].y;                 \
                Bs[(4 * c4 + 2) * PJ + row] = (double)pb[q].z;                 \
                Bs[(4 * c4 + 3) * PJ + row] = (double)pb[q].w;                 \
            }                                                                  \
            __syncthreads();                                                   \
            if (ck < 7) {                                                      \
                _Pragma("unroll")                                              \
                for (int q = 0; q < 2; q++) {                                  \
                    int flat = t + 256 * q;                                    \
                    int row = flat >> 2, c4 = flat & 3;                        \
                    pa[q] = X4[(size_t)(i0 + row) * 32 + (ck + 1) * 4 + c4];   \
                    pb[q] = X4[(size_t)(j0 + row) * 32 + (ck + 1) * 4 + c4];   \
                }                                                              \
            }                                                                  \
            _Pragma("unroll")                                                  \
            for (int ks = 0; ks < 4; ks++) {                                   \
                int cc = 4 * ks + g;                                           \
                double a0 = As[cc * PJ + w32 + r];                             \
                double a1 = As[cc * PJ + w32 + 16 + r];                        \
                double bv[8];                                                  \
                _Pragma("unroll")                                              \
                for (int nt = 0; nt < 8; nt++) bv[nt] = Bs[cc * PJ + nt * 16 + r]; \
                _Pragma("unroll")                                              \
                for (int nt = 0; nt < 8; nt++)                                 \
                    acc[0][nt] = __builtin_amdgcn_mfma_f64_16x16x4f64(a0, bv[nt], acc[0][nt], 0, 0, 0); \
                _Pragma("unroll")                                              \
                for (int nt = 0; nt < 8; nt++)                                 \
                    acc[1][nt] = __builtin_amdgcn_mfma_f64_16x16x4f64(a1, bv[nt], acc[1][nt], 0, 0, 0); \
            }                                                                  \
            __syncthreads();                                                   \
        }                                                                      \
    }

// lane-owned outputs: rows w32 + mt*16 + irow[j], cols nt*16 + r

// ---------------------------------------------------------------------------
// symA: MFMA d2 GEMM + sorted top-5 epilogue (rows bfly 1-8, cols 16/32+LDS).
// ---------------------------------------------------------------------------
__launch_bounds__(256, 2)
__global__ void symA_kernel(const float* __restrict__ X,
                            const double* __restrict__ sq,
                            double* __restrict__ rec_dir,
                            double* __restrict__ rec_tr,
                            unsigned long long* __restrict__ d2max_p)
{
    __shared__ __align__(16) double S[2 * CH * PJ];   // 33,280 B; reused as M
    double* As = S;
    double* Bs = S + CH * PJ;

    const int t = threadIdx.x;
    const int r = t & 15;
    const int g = (t >> 4) & 3;
    const int w = t >> 6;
    const int w32 = w * 32;
    int bi, bj;
    pair_decode(blockIdx.x, bi, bj);
    const int i0 = bi * TP, j0 = bj * TP;
    const float4* X4 = (const float4*)X;

    int irow[4];
    probe_rows(t, r, irow);

    d4 acc[2][8];
    #pragma unroll
    for (int mt = 0; mt < 2; mt++)
        #pragma unroll
        for (int nt = 0; nt < 8; nt++) acc[mt][nt] = (d4){0.0, 0.0, 0.0, 0.0};

    MFMA_GEMM_BODY(acc, As, Bs, X4, i0, j0, t, r, g, w32)

    // d2 in place + wave max -> global atomic
    double sqa[2][4], sqj[8];
    #pragma unroll
    for (int mt = 0; mt < 2; mt++)
        #pragma unroll
        for (int j = 0; j < 4; j++) sqa[mt][j] = sq[i0 + w32 + mt * 16 + irow[j]];
    #pragma unroll
    for (int nt = 0; nt < 8; nt++) sqj[nt] = sq[j0 + nt * 16 + r];
    double rmax = 0.0;
    #pragma unroll
    for (int mt = 0; mt < 2; mt++)
        #pragma unroll
        for (int nt = 0; nt < 8; nt++)
            #pragma unroll
            for (int j = 0; j < 4; j++) {
                double v = sqa[mt][j] + sqj[nt] - 2.0 * acc[mt][nt][j];
                acc[mt][nt][j] = v;
                rmax = fmax(rmax, v);
            }
    #pragma unroll
    for (int off = 32; off > 0; off >>= 1) rmax = fmax(rmax, __shfl_down(rmax, off, 64));
    if ((t & 63) == 0)
        atomicMax(d2max_p, (unsigned long long)__double_as_longlong(fmax(rmax, 0.0)));

    // ---- rows: lane scans 8 nt values; bfly over r lanes; r==0 writes.
    #pragma unroll
    for (int mt = 0; mt < 2; mt++)
        #pragma unroll
        for (int j = 0; j < 4; j++) {
            double m5[KNN];
            #pragma unroll
            for (int k = 0; k < KNN; k++) m5[k] = 1e300;
            #pragma unroll
            for (int nt = 0; nt < 8; nt++) ins5s(m5, acc[mt][nt][j]);
            bfly5s(m5, 1); bfly5s(m5, 2); bfly5s(m5, 4); bfly5s(m5, 8);
            if (r == 0) {
                int row = w32 + mt * 16 + irow[j];
                double* outp = &rec_dir[(size_t)blockIdx.x * (TP * KNN) + row * KNN];
                #pragma unroll
                for (int k = 0; k < KNN; k++) outp[k] = m5[k];
            }
        }

    // ---- cols (off-diagonal): scan 8 (mt,j); bfly over g (16,32); LDS merge
    if (bi != bj) {
        double* M = S;   // [col][21] : 4 wave-partials x 5
        #pragma unroll
        for (int nt = 0; nt < 8; nt++) {
            double m5[KNN];
            #pragma unroll
            for (int k = 0; k < KNN; k++) m5[k] = 1e300;
            #pragma unroll
            for (int mt = 0; mt < 2; mt++)
                #pragma unroll
                for (int j = 0; j < 4; j++) ins5s(m5, acc[mt][nt][j]);
            bfly5s(m5, 16); bfly5s(m5, 32);
            if (g == 0) {
                int col = nt * 16 + r;
                #pragma unroll
                for (int k = 0; k < KNN; k++) M[col * 21 + w * 5 + k] = m5[k];
            }
        }
        __syncthreads();
        if (t < 128) {
            double m5[KNN];
            #pragma unroll
            for (int k = 0; k < KNN; k++) m5[k] = M[t * 21 + k];
            merge5s(m5, &M[t * 21 + 5]);
            merge5s(m5, &M[t * 21 + 10]);
            merge5s(m5, &M[t * 21 + 15]);
            double* outp = &rec_tr[(size_t)blockIdx.x * (TP * KNN) + t * KNN];
            #pragma unroll
            for (int k = 0; k < KNN; k++) outp[k] = m5[k];
        }
    }
}

// ---------------------------------------------------------------------------
// Merge symA records -> density.  One WAVE per row; 64 lanes load the 64
// sorted records, 6 butterfly stages, lane 0 computes density.  (proven R16)
// ---------------------------------------------------------------------------
__global__ void density_merge_sym_kernel(const double* __restrict__ rec_dir,
                                         const double* __restrict__ rec_tr,
                                         const float* __restrict__ noise,
                                         double* __restrict__ density)
{
    int i = (blockIdx.x * blockDim.x + threadIdx.x) >> 6;   // row = global wave
    int l = threadIdx.x & 63;
    if (i >= N) return;
    int T = i >> 7, rr = i & 127;
    int ndir = NTILE - T;   // dir records: bj = T..63 ; tr records: b2 = 0..T-1
    double m5[KNN];
    if (l < ndir) {
        int bj = T + l;
        int p = bj * (bj + 1) / 2 + T;
        const double* rp = &rec_dir[(size_t)p * (TP * KNN) + rr * KNN];
        #pragma unroll
        for (int k = 0; k < KNN; k++) m5[k] = rp[k];
    } else {
        int b2 = l - ndir;   // < T  (ndir + T == 64, all lanes valid)
        int cumT = T * (T + 1) / 2;
        const double* rp = &rec_tr[(size_t)(cumT + b2) * (TP * KNN) + rr * KNN];
        #pragma unroll
        for (int k = 0; k < KNN; k++) m5[k] = rp[k];
    }
    bfly5s(m5, 1); bfly5s(m5, 2); bfly5s(m5, 4);
    bfly5s(m5, 8); bfly5s(m5, 16); bfly5s(m5, 32);
    if (l == 0) {
        double s2 = 0.0;
        #pragma unroll
        for (int k = 0; k < KNN; k++) {
            double z = m5[k] > 0.0 ? m5[k] : 0.0;
            double d = sqrt(z) / SQRT_C;
            s2 += d * d;
        }
        density[i] = exp(-s2 / 5.0) + (double)(noise[i] * 1e-6f);
    }
}

// ---------------------------------------------------------------------------
// symB: MFMA GEMM + masked row/col mins, shuffle-reduced, atomicMin.
// density read directly from global (L2-hot).  (R15 GEMM + R16 tail style)
// ---------------------------------------------------------------------------
__launch_bounds__(256, 2)
__global__ void symB_kernel(const float* __restrict__ X,
                            const double* __restrict__ sq,
                            const double* __restrict__ density,
                            unsigned long long* __restrict__ gmin)
{
    __shared__ __align__(16) double S[2 * CH * PJ];
    double* As = S;
    double* Bs = S + CH * PJ;

    const int t = threadIdx.x;
    const int r = t & 15;
    const int g = (t >> 4) & 3;
    const int w = t >> 6;
    const int w32 = w * 32;
    int bi, bj;
    pair_decode(blockIdx.x, bi, bj);
    const int i0 = bi * TP, j0 = bj * TP;
    const float4* X4 = (const float4*)X;

    int irow[4];
    probe_rows(t, r, irow);

    d4 acc[2][8];
    #pragma unroll
    for (int mt = 0; mt < 2; mt++)
        #pragma unroll
        for (int nt = 0; nt < 8; nt++) acc[mt][nt] = (d4){0.0, 0.0, 0.0, 0.0};

    MFMA_GEMM_BODY(acc, As, Bs, X4, i0, j0, t, r, g, w32)

    double sqa[2][4], di[2][4], sqj[8], dj[8], dmr[2][4], dmc[8];
    #pragma unroll
    for (int mt = 0; mt < 2; mt++)
        #pragma unroll
        for (int j = 0; j < 4; j++) {
            int row = w32 + mt * 16 + irow[j];
            sqa[mt][j] = sq[i0 + row];
            di[mt][j] = density[i0 + row];
            dmr[mt][j] = 1e300;
        }
    #pragma unroll
    for (int nt = 0; nt < 8; nt++) {
        int col = nt * 16 + r;
        sqj[nt] = sq[j0 + col];
        dj[nt] = density[j0 + col];
        dmc[nt] = 1e300;
    }

    #pragma unroll
    for (int mt = 0; mt < 2; mt++)
        #pragma unroll
        for (int nt = 0; nt < 8; nt++)
            #pragma unroll
            for (int j = 0; j < 4; j++) {
                double v = sqa[mt][j] + sqj[nt] - 2.0 * acc[mt][nt][j];
                if (dj[nt] > di[mt][j]) dmr[mt][j] = fmin(dmr[mt][j], v);
                if (di[mt][j] > dj[nt]) dmc[nt] = fmin(dmc[nt], v);
            }

    // rows: scalar min butterfly over r lanes; r==0 atomicMin
    #pragma unroll
    for (int mt = 0; mt < 2; mt++)
        #pragma unroll
        for (int j = 0; j < 4; j++) {
            #pragma unroll
            for (int m = 1; m <= 8; m <<= 1)
                dmr[mt][j] = fmin(dmr[mt][j], __shfl_xor(dmr[mt][j], m, 64));
        }
    if (r == 0) {
        #pragma unroll
        for (int mt = 0; mt < 2; mt++)
            #pragma unroll
            for (int j = 0; j < 4; j++)
                if (dmr[mt][j] < 9.9e299) {
                    int row = w32 + mt * 16 + irow[j];
                    atomicMin(&gmin[i0 + row], dmap(dmr[mt][j]));
                }
    }
    // cols: butterfly over g (16,32); g==0 atomicMin (4 wave-partials/col)
    if (bi != bj) {
        #pragma unroll
        for (int nt = 0; nt < 8; nt++) {
            #pragma unroll
            for (int m = 16; m <= 32; m <<= 1)
                dmc[nt] = fmin(dmc[nt], __shfl_xor(dmc[nt], m, 64));
        }
        if (g == 0) {
            #pragma unroll
            for (int nt = 0; nt < 8; nt++)
                if (dmc[nt] < 9.9e299) {
                    int col = nt * 16 + r;
                    atomicMin(&gmin[j0 + col], dmap(dmc[nt]));
                }
        }
    }
}

// ---------------------------------------------------------------------------
__global__ void score_sym_kernel(const unsigned long long* __restrict__ gmin,
                                 const double* __restrict__ density,
                                 const unsigned long long* __restrict__ d2max_p,
                                 double* __restrict__ score)
{
    int i = blockIdx.x * blockDim.x + threadIdx.x;
    if (i >= N) return;
    unsigned long long u = gmin[i];
    double d2m = __longlong_as_double((long long)(*d2max_p));
    double distmax = sqrt(fmax(d2m, 0.0)) / SQRT_C;
    double dp;
    if (u == 0xFFFFFFFFFFFFFFFFull) {
        dp = distmax;
    } else {
        double dmin = dunmap(u);
        dp = sqrt(fmax(dmin, 0.0)) / SQRT_C;
    }
    score[i] = dp * density[i];
}

// ---------------------------------------------------------------------------
// Stable descending rank; 256 blocks, 8-way j-split per row, shuffle reduce.
// ---------------------------------------------------------------------------
__launch_bounds__(256)
__global__ void rank_kernel(const double* __restrict__ score, int* __restrict__ out)
{
    __shared__ double Ss[N];   // 64 KB
    for (int k = 0; k < N / 256; k++) {
        int idx = threadIdx.x + 256 * k;
        Ss[idx] = score[idx];
    }
    __syncthreads();
    int il = threadIdx.x >> 3;          // 0..31
    int ch = threadIdx.x & 7;           // 0..7
    int i = blockIdx.x * 32 + il;
    double si = Ss[i];
    int cnt = 0;
    for (int q = 0; q < N / 8; q++) {
        int j = ch + (q << 3);
        double sj = Ss[j];
        cnt += (sj > si) || (sj == si && j < i);
    }
    cnt += __shfl_down(cnt, 4, 8);
    cnt += __shfl_down(cnt, 2, 8);
    cnt += __shfl_down(cnt, 1, 8);
    if (ch == 0 && cnt < NC) out[cnt] = i;
}

// ---------------------------------------------------------------------------
extern "C" void kernel_launch(void* const* d_in, const int* in_sizes, int n_in,
                              void* d_out, int out_size, void* d_ws, size_t ws_size,
                              hipStream_t stream) {
    const float* X = (const float*)d_in[0];
    int* out = (int*)d_out;

    double* ws      = (double*)d_ws;
    double* sq      = ws;                      // 8192
    double* density = ws + 8192;               // 8192
    double* score   = ws + 16384;              // 8192
    unsigned long long* d2max = (unsigned long long*)(ws + 24576);
    unsigned long long* gmin  = (unsigned long long*)(ws + 24584);  // 8192
    float*  noise   = (float*)(ws + 32776);    // 8192 floats

    const size_t rec_bytes = (size_t)NPAIR * TP * KNN * sizeof(double);  // 10.65 MB
    const size_t base_need = 4ull * 1024 * 1024;
    double* rec_dir = (double*)((char*)d_ws + base_need);
    double* rec_tr  = (double*)((char*)d_ws + base_need + rec_bytes);

    init_kernel<<<N / 256, 256, 0, stream>>>(d2max, gmin);
    sq_kernel<<<N / 4, 256, 0, stream>>>(X, sq);
    noise_kernel<<<(N / 2) / 256, 256, 0, stream>>>(noise);

    symA_kernel<<<NPAIR, 256, 0, stream>>>(X, sq, rec_dir, rec_tr, d2max);
    density_merge_sym_kernel<<<N * 64 / 256, 256, 0, stream>>>(rec_dir, rec_tr, noise, density);
    symB_kernel<<<NPAIR, 256, 0, stream>>>(X, sq, density, gmin);
    score_sym_kernel<<<N / 256, 256, 0, stream>>>(gmin, density, d2max, score);
    rank_kernel<<<N / 32, 256, 0, stream>>>(score, out);
}

// Round 19
// 477.930 us; speedup vs baseline: 1.3148x; 1.0316x over previous
//
#include <hip/hip_runtime.h>
#include <math.h>

#define N 8192
#define C 128
#define NC 256
#define KNN 5

#define TP 128                        // tile size
#define NTILE (N / TP)                // 64
#define NPAIR (NTILE * (NTILE + 1) / 2)   // 2080
#define CH 16                         // channels per staging chunk
#define PJ 130                        // LDS pitch over row-dim (doubles)
#define SQRT_C 11.313708498984761     // sqrt(128)

typedef double d4 __attribute__((ext_vector_type(4)));

static __device__ __forceinline__ unsigned rotl32(unsigned x, unsigned r) {
    return (x << r) | (x >> (32u - r));
}

// order-preserving double -> uint64 map (ascending)
static __device__ __forceinline__ unsigned long long dmap(double x) {
    long long b = __double_as_longlong(x);
    unsigned long long u = (unsigned long long)b;
    return (b >= 0) ? (u | 0x8000000000000000ull) : ~u;
}
static __device__ __forceinline__ double dunmap(unsigned long long u) {
    if (u & 0x8000000000000000ull) return __longlong_as_double((long long)(u ^ 0x8000000000000000ull));
    return __longlong_as_double((long long)(~u));
}

// ---------------------------------------------------------------------------
// Branchless sorted top-5 (ascending).  (proven R13)
static __device__ __forceinline__ void ins5s(double (&m)[KNN], double v) {
    m[4] = fmin(m[4], fmax(m[3], v));
    m[3] = fmin(m[3], fmax(m[2], v));
    m[2] = fmin(m[2], fmax(m[1], v));
    m[1] = fmin(m[1], fmax(m[0], v));
    m[0] = fmin(m[0], v);
}
static __device__ __forceinline__ void sort5(double (&m)[KNN]) {
    double lo, hi;
#define CE(i, j) lo = fmin(m[i], m[j]); hi = fmax(m[i], m[j]); m[i] = lo; m[j] = hi;
    CE(0,1) CE(3,4) CE(2,4) CE(2,3) CE(0,3) CE(0,2) CE(1,4) CE(1,3) CE(1,2)
#undef CE
}
// bitonic top-5 butterfly merge (snapshot-before-mutate)  (proven R13)
static __device__ __forceinline__ void bfly5s(double (&m)[KNN], int mask) {
    double pv[KNN];
    #pragma unroll
    for (int k = 0; k < KNN; k++) pv[k] = __shfl_xor(m[4 - k], mask, 64);
    #pragma unroll
    for (int k = 0; k < KNN; k++) m[k] = fmin(m[k], pv[k]);
    sort5(m);
}
static __device__ __forceinline__ void merge5s(double (&m)[KNN], const double* l) {
    #pragma unroll
    for (int k = 0; k < KNN; k++) m[k] = fmin(m[k], l[4 - k]);
    sort5(m);
}

// ---------------------------------------------------------------------------
// f64 MFMA D-layout probe (proven R15): A[m][k]=m, B[k][n]=[n==0] -> D[i][0]=4i.
static __device__ __forceinline__ void probe_rows(int t, int r, int (&irow)[4]) {
    d4 pd = (d4){0.0, 0.0, 0.0, 0.0};
    pd = __builtin_amdgcn_mfma_f64_16x16x4f64((double)r, (r == 0) ? 1.0 : 0.0,
                                              pd, 0, 0, 0);
    #pragma unroll
    for (int j = 0; j < 4; j++) {
        double rv = __shfl(pd[j], t & 48, 64);   // group root lane 16*g
        irow[j] = (int)(rv * 0.25);
    }
}

// ---------------------------------------------------------------------------
// Fused setup: sq (one wave per row) + gmin/d2max init + threefry noise.
// All independent writes; identical work every call (graph-safe).
// ---------------------------------------------------------------------------
__global__ void setup_kernel(const float* __restrict__ X,
                             double* __restrict__ sq,
                             unsigned long long* __restrict__ d2max,
                             unsigned long long* __restrict__ gmin,
                             float* __restrict__ noise)
{
    int gid = blockIdx.x * blockDim.x + threadIdx.x;
    int wave = gid >> 6;
    int lane = threadIdx.x & 63;

    // sq
    if (wave < N) {
        double v0 = (double)X[wave * C + lane];
        double v1 = (double)X[wave * C + 64 + lane];
        double s = v0 * v0 + v1 * v1;
        #pragma unroll
        for (int off = 32; off > 0; off >>= 1) s += __shfl_down(s, off, 64);
        if (lane == 0) sq[wave] = s;
    }
    // gmin init
    if (gid < N) gmin[gid] = 0xFFFFFFFFFFFFFFFFull;
    if (gid == 0) *d2max = 0ull;
    // threefry noise: uniform(key(1), (1,8192)); counts split (j, j+4096)
    if (gid < N / 2) {
        int j = gid;
        const unsigned ks0 = 0u, ks1 = 1u;
        const unsigned ks2 = 0x1BD11BDAu ^ ks0 ^ ks1;
        unsigned x0 = (unsigned)j + ks0;
        unsigned x1 = (unsigned)(j + N / 2) + ks1;
        const unsigned rotA[4] = {13u, 15u, 26u, 6u};
        const unsigned rotB[4] = {17u, 29u, 16u, 24u};
        #pragma unroll
        for (int q = 0; q < 4; q++) { x0 += x1; x1 = rotl32(x1, rotA[q]); x1 ^= x0; }
        x0 += ks1; x1 += ks2 + 1u;
        #pragma unroll
        for (int q = 0; q < 4; q++) { x0 += x1; x1 = rotl32(x1, rotB[q]); x1 ^= x0; }
        x0 += ks2; x1 += ks0 + 2u;
        #pragma unroll
        for (int q = 0; q < 4; q++) { x0 += x1; x1 = rotl32(x1, rotA[q]); x1 ^= x0; }
        x0 += ks0; x1 += ks1 + 3u;
        #pragma unroll
        for (int q = 0; q < 4; q++) { x0 += x1; x1 = rotl32(x1, rotB[q]); x1 ^= x0; }
        x0 += ks1; x1 += ks2 + 4u;
        #pragma unroll
        for (int q = 0; q < 4; q++) { x0 += x1; x1 = rotl32(x1, rotA[q]); x1 ^= x0; }
        x0 += ks2; x1 += ks0 + 5u;
        unsigned b0 = (x0 >> 9) | 0x3f800000u;
        unsigned b1 = (x1 >> 9) | 0x3f800000u;
        noise[j]         = __uint_as_float(b0) - 1.0f;
        noise[j + N / 2] = __uint_as_float(b1) - 1.0f;
    }
}

// p = bj*(bj+1)/2 + bi, bi <= bj
static __device__ __forceinline__ void pair_decode(int p, int& bi, int& bj) {
    int b = (int)((sqrt(8.0 * (double)p + 1.0) - 1.0) * 0.5);
    while ((b + 1) * (b + 2) / 2 <= p) b++;
    while (b * (b + 1) / 2 > p) b--;
    bj = b;
    bi = p - b * (b + 1) / 2;
}

// ---------------------------------------------------------------------------
// MFMA f64 GEMM body (R15/R18, proven): 128x128 tile-pair.
// Wave w owns rows w*32..w*32+31 (2 row-tiles) x all 128 cols (8 col-tiles).
// acc[2][8] d4/lane.  f64 [c][row] staging (pitch PJ), 8 chunks of 16
// channels, register prefetch.  A: m=l&15,k=l>>4 ; B: k=l>>4,n=l&15 ;
// D: col=l&15, row via probe_rows.
// ---------------------------------------------------------------------------
#define MFMA_GEMM_BODY(acc, As, Bs, X4, i0, j0, t, r, g, w32)                  \
    {                                                                          \
        float4 pa[2], pb[2];                                                   \
        _Pragma("unroll")                                                      \
        for (int q = 0; q < 2; q++) {                                          \
            int flat = t + 256 * q;                                            \
            int row = flat >> 2, c4 = flat & 3;                                \
            pa[q] = X4[(size_t)(i0 + row) * 32 + c4];                          \
            pb[q] = X4[(size_t)(j0 + row) * 32 + c4];                          \
        }                                                                      \
        for (int ck = 0; ck < 8; ck++) {                                       \
            _Pragma("unroll")                                                  \
            for (int q = 0; q < 2; q++) {                                      \
                int flat = t + 256 * q;                                        \
                int row = flat >> 2, c4 = flat & 3;                            \
                As[(4 * c4 + 0) * PJ + row] = (double)pa[q].x;                 \
                As[(4 * c4 + 1) * PJ + row] = (double)pa[q].y;                 \
                As[(4 * c4 + 2) * PJ + row] = (double)pa[q].z;                 \
                As[(4 * c4 + 3) * PJ + row] = (double)pa[q].w;                 \
                Bs[(4 * c4 + 0) * PJ + row] = (double)pb[q].x;                 \
                Bs[(4 * c4 + 1) * PJ + row] = (double)pb[q].y;                 \
                Bs[(4 * c4 + 2) * PJ + row] = (double)pb[q].z;                 \
                Bs[(4 * c4 + 3) * PJ + row] = (double)pb[q].w;                 \
            }                                                                  \
            __syncthreads();                                                   \
            if (ck < 7) {                                                      \
                _Pragma("unroll")                                              \
                for (int q = 0; q < 2; q++) {                                  \
                    int flat = t + 256 * q;                                    \
                    int row = flat >> 2, c4 = flat & 3;                        \
                    pa[q] = X4[(size_t)(i0 + row) * 32 + (ck + 1) * 4 + c4];   \
                    pb[q] = X4[(size_t)(j0 + row) * 32 + (ck + 1) * 4 + c4];   \
                }                                                              \
            }                                                                  \
            _Pragma("unroll")                                                  \
            for (int ks = 0; ks < 4; ks++) {                                   \
                int cc = 4 * ks + g;                                           \
                double a0 = As[cc * PJ + w32 + r];                             \
                double a1 = As[cc * PJ + w32 + 16 + r];                        \
                double bv[8];                                                  \
                _Pragma("unroll")                                              \
                for (int nt = 0; nt < 8; nt++) bv[nt] = Bs[cc * PJ + nt * 16 + r]; \
                _Pragma("unroll")                                              \
                for (int nt = 0; nt < 8; nt++)                                 \
                    acc[0][nt] = __builtin_amdgcn_mfma_f64_16x16x4f64(a0, bv[nt], acc[0][nt], 0, 0, 0); \
                _Pragma("unroll")                                              \
                for (int nt = 0; nt < 8; nt++)                                 \
                    acc[1][nt] = __builtin_amdgcn_mfma_f64_16x16x4f64(a1, bv[nt], acc[1][nt], 0, 0, 0); \
            }                                                                  \
            __syncthreads();                                                   \
        }                                                                      \
    }

// lane-owned outputs: rows w32 + mt*16 + irow[j], cols nt*16 + r

// ---------------------------------------------------------------------------
// symA: MFMA d2 GEMM + sorted top-5 epilogue (rows bfly 1-8, cols 16/32+LDS).
// ---------------------------------------------------------------------------
__launch_bounds__(256, 2)
__global__ void symA_kernel(const float* __restrict__ X,
                            const double* __restrict__ sq,
                            double* __restrict__ rec_dir,
                            double* __restrict__ rec_tr,
                            unsigned long long* __restrict__ d2max_p)
{
    __shared__ __align__(16) double S[2 * CH * PJ];   // 33,280 B; reused as M
    double* As = S;
    double* Bs = S + CH * PJ;

    const int t = threadIdx.x;
    const int r = t & 15;
    const int g = (t >> 4) & 3;
    const int w = t >> 6;
    const int w32 = w * 32;
    int bi, bj;
    pair_decode(blockIdx.x, bi, bj);
    const int i0 = bi * TP, j0 = bj * TP;
    const float4* X4 = (const float4*)X;

    int irow[4];
    probe_rows(t, r, irow);

    d4 acc[2][8];
    #pragma unroll
    for (int mt = 0; mt < 2; mt++)
        #pragma unroll
        for (int nt = 0; nt < 8; nt++) acc[mt][nt] = (d4){0.0, 0.0, 0.0, 0.0};

    MFMA_GEMM_BODY(acc, As, Bs, X4, i0, j0, t, r, g, w32)

    // d2 in place + wave max -> global atomic
    double sqa[2][4], sqj[8];
    #pragma unroll
    for (int mt = 0; mt < 2; mt++)
        #pragma unroll
        for (int j = 0; j < 4; j++) sqa[mt][j] = sq[i0 + w32 + mt * 16 + irow[j]];
    #pragma unroll
    for (int nt = 0; nt < 8; nt++) sqj[nt] = sq[j0 + nt * 16 + r];
    double rmax = 0.0;
    #pragma unroll
    for (int mt = 0; mt < 2; mt++)
        #pragma unroll
        for (int nt = 0; nt < 8; nt++)
            #pragma unroll
            for (int j = 0; j < 4; j++) {
                double v = sqa[mt][j] + sqj[nt] - 2.0 * acc[mt][nt][j];
                acc[mt][nt][j] = v;
                rmax = fmax(rmax, v);
            }
    #pragma unroll
    for (int off = 32; off > 0; off >>= 1) rmax = fmax(rmax, __shfl_down(rmax, off, 64));
    if ((t & 63) == 0)
        atomicMax(d2max_p, (unsigned long long)__double_as_longlong(fmax(rmax, 0.0)));

    // ---- rows: lane scans 8 nt values; bfly over r lanes; r==0 writes.
    #pragma unroll
    for (int mt = 0; mt < 2; mt++)
        #pragma unroll
        for (int j = 0; j < 4; j++) {
            double m5[KNN];
            #pragma unroll
            for (int k = 0; k < KNN; k++) m5[k] = 1e300;
            #pragma unroll
            for (int nt = 0; nt < 8; nt++) ins5s(m5, acc[mt][nt][j]);
            bfly5s(m5, 1); bfly5s(m5, 2); bfly5s(m5, 4); bfly5s(m5, 8);
            if (r == 0) {
                int row = w32 + mt * 16 + irow[j];
                double* outp = &rec_dir[(size_t)blockIdx.x * (TP * KNN) + row * KNN];
                #pragma unroll
                for (int k = 0; k < KNN; k++) outp[k] = m5[k];
            }
        }

    // ---- cols (off-diagonal): scan 8 (mt,j); bfly over g (16,32); LDS merge
    if (bi != bj) {
        double* M = S;   // [col][21] : 4 wave-partials x 5
        #pragma unroll
        for (int nt = 0; nt < 8; nt++) {
            double m5[KNN];
            #pragma unroll
            for (int k = 0; k < KNN; k++) m5[k] = 1e300;
            #pragma unroll
            for (int mt = 0; mt < 2; mt++)
                #pragma unroll
                for (int j = 0; j < 4; j++) ins5s(m5, acc[mt][nt][j]);
            bfly5s(m5, 16); bfly5s(m5, 32);
            if (g == 0) {
                int col = nt * 16 + r;
                #pragma unroll
                for (int k = 0; k < KNN; k++) M[col * 21 + w * 5 + k] = m5[k];
            }
        }
        __syncthreads();
        if (t < 128) {
            double m5[KNN];
            #pragma unroll
            for (int k = 0; k < KNN; k++) m5[k] = M[t * 21 + k];
            merge5s(m5, &M[t * 21 + 5]);
            merge5s(m5, &M[t * 21 + 10]);
            merge5s(m5, &M[t * 21 + 15]);
            double* outp = &rec_tr[(size_t)blockIdx.x * (TP * KNN) + t * KNN];
            #pragma unroll
            for (int k = 0; k < KNN; k++) outp[k] = m5[k];
        }
    }
}

// ---------------------------------------------------------------------------
// Merge symA records -> density.  One WAVE per row; 64 lanes load the 64
// sorted records, 6 butterfly stages, lane 0 computes density.  (proven R16)
// ---------------------------------------------------------------------------
__global__ void density_merge_sym_kernel(const double* __restrict__ rec_dir,
                                         const double* __restrict__ rec_tr,
                                         const float* __restrict__ noise,
                                         double* __restrict__ density)
{
    int i = (blockIdx.x * blockDim.x + threadIdx.x) >> 6;   // row = global wave
    int l = threadIdx.x & 63;
    if (i >= N) return;
    int T = i >> 7, rr = i & 127;
    int ndir = NTILE - T;   // dir records: bj = T..63 ; tr records: b2 = 0..T-1
    double m5[KNN];
    if (l < ndir) {
        int bj = T + l;
        int p = bj * (bj + 1) / 2 + T;
        const double* rp = &rec_dir[(size_t)p * (TP * KNN) + rr * KNN];
        #pragma unroll
        for (int k = 0; k < KNN; k++) m5[k] = rp[k];
    } else {
        int b2 = l - ndir;   // < T  (ndir + T == 64, all lanes valid)
        int cumT = T * (T + 1) / 2;
        const double* rp = &rec_tr[(size_t)(cumT + b2) * (TP * KNN) + rr * KNN];
        #pragma unroll
        for (int k = 0; k < KNN; k++) m5[k] = rp[k];
    }
    bfly5s(m5, 1); bfly5s(m5, 2); bfly5s(m5, 4);
    bfly5s(m5, 8); bfly5s(m5, 16); bfly5s(m5, 32);
    if (l == 0) {
        double s2 = 0.0;
        #pragma unroll
        for (int k = 0; k < KNN; k++) {
            double z = m5[k] > 0.0 ? m5[k] : 0.0;
            double d = sqrt(z) / SQRT_C;
            s2 += d * d;
        }
        density[i] = exp(-s2 / 5.0) + (double)(noise[i] * 1e-6f);
    }
}

// ---------------------------------------------------------------------------
// symB: MFMA GEMM + masked row/col mins, shuffle-reduced, atomicMin.
// density read directly from global (L2-hot).
// ---------------------------------------------------------------------------
__launch_bounds__(256, 2)
__global__ void symB_kernel(const float* __restrict__ X,
                            const double* __restrict__ sq,
                            const double* __restrict__ density,
                            unsigned long long* __restrict__ gmin)
{
    __shared__ __align__(16) double S[2 * CH * PJ];
    double* As = S;
    double* Bs = S + CH * PJ;

    const int t = threadIdx.x;
    const int r = t & 15;
    const int g = (t >> 4) & 3;
    const int w = t >> 6;
    const int w32 = w * 32;
    int bi, bj;
    pair_decode(blockIdx.x, bi, bj);
    const int i0 = bi * TP, j0 = bj * TP;
    const float4* X4 = (const float4*)X;

    int irow[4];
    probe_rows(t, r, irow);

    d4 acc[2][8];
    #pragma unroll
    for (int mt = 0; mt < 2; mt++)
        #pragma unroll
        for (int nt = 0; nt < 8; nt++) acc[mt][nt] = (d4){0.0, 0.0, 0.0, 0.0};

    MFMA_GEMM_BODY(acc, As, Bs, X4, i0, j0, t, r, g, w32)

    double sqa[2][4], di[2][4], sqj[8], dj[8], dmr[2][4], dmc[8];
    #pragma unroll
    for (int mt = 0; mt < 2; mt++)
        #pragma unroll
        for (int j = 0; j < 4; j++) {
            int row = w32 + mt * 16 + irow[j];
            sqa[mt][j] = sq[i0 + row];
            di[mt][j] = density[i0 + row];
            dmr[mt][j] = 1e300;
        }
    #pragma unroll
    for (int nt = 0; nt < 8; nt++) {
        int col = nt * 16 + r;
        sqj[nt] = sq[j0 + col];
        dj[nt] = density[j0 + col];
        dmc[nt] = 1e300;
    }

    #pragma unroll
    for (int mt = 0; mt < 2; mt++)
        #pragma unroll
        for (int nt = 0; nt < 8; nt++)
            #pragma unroll
            for (int j = 0; j < 4; j++) {
                double v = sqa[mt][j] + sqj[nt] - 2.0 * acc[mt][nt][j];
                if (dj[nt] > di[mt][j]) dmr[mt][j] = fmin(dmr[mt][j], v);
                if (di[mt][j] > dj[nt]) dmc[nt] = fmin(dmc[nt], v);
            }

    // rows: scalar min butterfly over r lanes; r==0 atomicMin
    #pragma unroll
    for (int mt = 0; mt < 2; mt++)
        #pragma unroll
        for (int j = 0; j < 4; j++) {
            #pragma unroll
            for (int m = 1; m <= 8; m <<= 1)
                dmr[mt][j] = fmin(dmr[mt][j], __shfl_xor(dmr[mt][j], m, 64));
        }
    if (r == 0) {
        #pragma unroll
        for (int mt = 0; mt < 2; mt++)
            #pragma unroll
            for (int j = 0; j < 4; j++)
                if (dmr[mt][j] < 9.9e299) {
                    int row = w32 + mt * 16 + irow[j];
                    atomicMin(&gmin[i0 + row], dmap(dmr[mt][j]));
                }
    }
    // cols: butterfly over g (16,32); g==0 atomicMin (4 wave-partials/col)
    if (bi != bj) {
        #pragma unroll
        for (int nt = 0; nt < 8; nt++) {
            #pragma unroll
            for (int m = 16; m <= 32; m <<= 1)
                dmc[nt] = fmin(dmc[nt], __shfl_xor(dmc[nt], m, 64));
        }
        if (g == 0) {
            #pragma unroll
            for (int nt = 0; nt < 8; nt++)
                if (dmc[nt] < 9.9e299) {
                    int col = nt * 16 + r;
                    atomicMin(&gmin[j0 + col], dmap(dmc[nt]));
                }
        }
    }
}

// ---------------------------------------------------------------------------
__global__ void score_sym_kernel(const unsigned long long* __restrict__ gmin,
                                 const double* __restrict__ density,
                                 const unsigned long long* __restrict__ d2max_p,
                                 double* __restrict__ score)
{
    int i = blockIdx.x * blockDim.x + threadIdx.x;
    if (i >= N) return;
    unsigned long long u = gmin[i];
    double d2m = __longlong_as_double((long long)(*d2max_p));
    double distmax = sqrt(fmax(d2m, 0.0)) / SQRT_C;
    double dp;
    if (u == 0xFFFFFFFFFFFFFFFFull) {
        dp = distmax;
    } else {
        double dmin = dunmap(u);
        dp = sqrt(fmax(dmin, 0.0)) / SQRT_C;
    }
    score[i] = dp * density[i];
}

// ---------------------------------------------------------------------------
// Stable descending rank; 512 blocks, 16-way j-split per row, shuffle reduce.
// ---------------------------------------------------------------------------
__launch_bounds__(256)
__global__ void rank_kernel(const double* __restrict__ score, int* __restrict__ out)
{
    __shared__ double Ss[N];   // 64 KB
    for (int k = 0; k < N / 256; k++) {
        int idx = threadIdx.x + 256 * k;
        Ss[idx] = score[idx];
    }
    __syncthreads();
    int il = threadIdx.x >> 4;          // 0..15
    int ch = threadIdx.x & 15;          // 0..15
    int i = blockIdx.x * 16 + il;
    double si = Ss[i];
    int cnt = 0;
    for (int q = 0; q < N / 16; q++) {
        int j = ch + (q << 4);
        double sj = Ss[j];
        cnt += (sj > si) || (sj == si && j < i);
    }
    cnt += __shfl_down(cnt, 8, 16);
    cnt += __shfl_down(cnt, 4, 16);
    cnt += __shfl_down(cnt, 2, 16);
    cnt += __shfl_down(cnt, 1, 16);
    if (ch == 0 && cnt < NC) out[cnt] = i;
}

// ---------------------------------------------------------------------------
extern "C" void kernel_launch(void* const* d_in, const int* in_sizes, int n_in,
                              void* d_out, int out_size, void* d_ws, size_t ws_size,
                              hipStream_t stream) {
    const float* X = (const float*)d_in[0];
    int* out = (int*)d_out;

    double* ws      = (double*)d_ws;
    double* sq      = ws;                      // 8192
    double* density = ws + 8192;               // 8192
    double* score   = ws + 16384;              // 8192
    unsigned long long* d2max = (unsigned long long*)(ws + 24576);
    unsigned long long* gmin  = (unsigned long long*)(ws + 24584);  // 8192
    float*  noise   = (float*)(ws + 32776);    // 8192 floats

    const size_t rec_bytes = (size_t)NPAIR * TP * KNN * sizeof(double);  // 10.65 MB
    const size_t base_need = 4ull * 1024 * 1024;
    double* rec_dir = (double*)((char*)d_ws + base_need);
    double* rec_tr  = (double*)((char*)d_ws + base_need + rec_bytes);

    setup_kernel<<<N / 4, 256, 0, stream>>>(X, sq, d2max, gmin, noise);
    symA_kernel<<<NPAIR, 256, 0, stream>>>(X, sq, rec_dir, rec_tr, d2max);
    density_merge_sym_kernel<<<N * 64 / 256, 256, 0, stream>>>(rec_dir, rec_tr, noise, density);
    symB_kernel<<<NPAIR, 256, 0, stream>>>(X, sq, density, gmin);
    score_sym_kernel<<<N / 256, 256, 0, stream>>>(gmin, density, d2max, score);
    rank_kernel<<<N / 16, 256, 0, stream>>>(score, out);
}